// Round 22
// baseline (222.673 us; speedup 1.0000x reference)
//
#include <hip/hip_runtime.h>
#include <math.h>

#define SEQ 2048
#define BSZ 2
#define DM 512
#define DIN 1024
#define DSTATE 16
#define NH 16
#define HD 64
#define CONVDIM 1056
#define DINPROJ 2096
#define DFF 2048
#define ROWS (BSZ*SEQ)
#define NCH 32
#define CT  (SEQ/NCH)     // 64
#define ZXW 2176          // padded zx row width (bf16)
// per-direction strides (element counts)
#define ZXBN 8912896ull   // shorts: 4096 x 2176 bf16
#define BCN 65536ull
#define DTN 65536ull
#define YN  4194304ull    // shorts (bf16 scan y, includes D*x)
#define HSN 1048576ull    // floats: per-dir chunk summaries (32bh x 32ch x 1024)

typedef short bf16x8 __attribute__((ext_vector_type(8)));
typedef float f32x4  __attribute__((ext_vector_type(4)));
typedef unsigned short u16x8 __attribute__((ext_vector_type(8)));

__device__ __forceinline__ float sigf(float x){ return 1.f/(1.f+expf(-x)); }

__device__ __forceinline__ unsigned short f2bf(float f){
  union { float f; unsigned u; } v; v.f = f;
  unsigned r = (v.u + 0x7FFFu + ((v.u >> 16) & 1u)) >> 16;
  return (unsigned short)r;
}
__device__ __forceinline__ float bf2f(unsigned short h){
  union { unsigned u; float f; } v; v.u = ((unsigned)h) << 16;
  return v.f;
}

template<int N> __device__ __forceinline__ void s_wait_vmcnt(){
  if constexpr (N == 0)      asm volatile("s_waitcnt vmcnt(0)" ::: "memory");
  else if constexpr (N == 1) asm volatile("s_waitcnt vmcnt(1)" ::: "memory");
  else if constexpr (N == 2) asm volatile("s_waitcnt vmcnt(2)" ::: "memory");
  else if constexpr (N == 3) asm volatile("s_waitcnt vmcnt(3)" ::: "memory");
  else if constexpr (N == 4) asm volatile("s_waitcnt vmcnt(4)" ::: "memory");
  else                       asm volatile("s_waitcnt vmcnt(8)" ::: "memory");
}

__device__ __forceinline__ float wave_reduce(float v){
#pragma unroll
  for (int o = 32; o > 0; o >>= 1) v += __shfl_down(v, o);
  return v;
}

__device__ __forceinline__ float block_reduce_256(float v, float* sbuf){
  v = wave_reduce(v);
  int lane = threadIdx.x & 63, wid = threadIdx.x >> 6;
  if (lane == 0) sbuf[wid] = v;
  __syncthreads();
  float s = sbuf[0] + sbuf[1] + sbuf[2] + sbuf[3];
  __syncthreads();
  return s;
}

// ---------------- weight cast + N-pad to bf16 (inproj pair) ----------------
__global__ __launch_bounds__(256)
void castpad2_k(const float* __restrict__ in0, const float* __restrict__ in1,
                unsigned short* __restrict__ out0, unsigned short* __restrict__ out1,
                int N, int K, int Npad){
  int tot = Npad*K;
  int idx = blockIdx.x*256 + threadIdx.x;
  const float* in = in0; unsigned short* out = out0;
  if (idx >= tot){ idx -= tot; in = in1; out = out1; }
  if (idx >= tot) return;
  int n = idx / K, k = idx - n*K;
  out[idx] = (n < N) ? f2bf(in[(size_t)n*K + k]) : (unsigned short)0;
}

// ---------------- flat weight casts (4 segments) ----------------
struct Cast6 {
  const float* src[6];
  unsigned short* dst[6];
  int n[6];
};
__global__ __launch_bounds__(256)
void cast6_k(Cast6 cp){
  int seg = blockIdx.y;
  int n4 = cp.n[seg] >> 2;
  int i = blockIdx.x*256 + threadIdx.x;
  if (i >= n4) return;
  const float* src = cp.src[seg];
  unsigned short* dst = cp.dst[seg];
  float4 v = *(const float4*)&src[i*4];
  ushort4 o;
  o.x = f2bf(v.x); o.y = f2bf(v.y); o.z = f2bf(v.z); o.w = f2bf(v.w);
  *(ushort4*)&dst[i*4] = o;
}

// ---------------- rmsnorm over D=512, writes fp32 + bf16 ----------------
__global__ __launch_bounds__(256)
void rmsnorm512_k(const float* __restrict__ x, const float* __restrict__ w,
                  float* __restrict__ y, unsigned short* __restrict__ yb, float eps){
  __shared__ float sbuf[4];
  int r = blockIdx.x;
  const float* xr = x + (size_t)r*DM;
  float v0 = xr[threadIdx.x];
  float v1 = xr[threadIdx.x + 256];
  float ss = block_reduce_256(v0*v0 + v1*v1, sbuf);
  float rs = rsqrtf(ss*(1.f/DM) + eps);
  float o0 = w[threadIdx.x]*v0*rs;
  float o1 = w[threadIdx.x+256]*v1*rs;
  y[(size_t)r*DM + threadIdx.x]       = o0;
  y[(size_t)r*DM + threadIdx.x + 256] = o1;
  yb[(size_t)r*DM + threadIdx.x]       = f2bf(o0);
  yb[(size_t)r*DM + threadIdx.x + 256] = f2bf(o1);
}

// ---------------- gated fusion (query rows, updates fp32 + bf16) ----------------
__global__ __launch_bounds__(256)
void gated_fusion_k(float* __restrict__ h, unsigned short* __restrict__ hb,
                    const float* __restrict__ wfc_w, const float* __restrict__ wfc_b,
                    const float* __restrict__ gfc_w, const float* __restrict__ gfc_b){
  int c = blockIdx.x;
  float* base = h + (size_t)c*16*DM;
  float* qrow = base + 15*DM;
  unsigned short* qrow_b = hb + (size_t)c*16*DM + 15*DM;
  __shared__ float q[DM];
  __shared__ float dots[16];
  for (int i = threadIdx.x; i < DM; i += 256) q[i] = qrow[i];
  __syncthreads();
  int wid = threadIdx.x >> 6, lane = threadIdx.x & 63;
  for (int f = wid; f < 16; f += 4){
    const float* wf = (f < 15) ? (wfc_w + (size_t)f*DM) : gfc_w;
    float s = 0.f;
    for (int i = lane; i < DM; i += 64) s += q[i]*wf[i];
    s = wave_reduce(s);
    if (lane == 0) dots[f] = s;
  }
  __syncthreads();
  if (threadIdx.x == 0){
    float mx = -1e30f;
    for (int f = 0; f < 15; f++){ dots[f] += wfc_b[f]; mx = fmaxf(mx, dots[f]); }
    float sum = 0.f;
    for (int f = 0; f < 15; f++){ float e = expf(dots[f]-mx); dots[f] = e; sum += e; }
    float inv = 1.f/sum;
    for (int f = 0; f < 15; f++) dots[f] *= inv;
    float g = sigf(dots[15] + gfc_b[0]);
    dots[15] = g*0.98f + 0.01f;
  }
  __syncthreads();
  float gate = dots[15];
  for (int d = threadIdx.x; d < DM; d += 256){
    float agg = 0.f;
#pragma unroll
    for (int f = 0; f < 15; f++) agg += base[(size_t)f*DM + d]*dots[f];
    float qn = q[d]*(1.f-gate) + agg*gate;
    qrow[d] = qn;
    qrow_b[d] = f2bf(qn);
  }
}

// ---------------- MFMA bf16 GEMM, counted-vmcnt pipeline + XCD swizzle ----------------
template<int NW, int WM, int WN, int FM, int FN, int DEPTH, int NBUF>
__global__ __launch_bounds__(NW*64)
void mgemm_k(const unsigned short* __restrict__ A, size_t Astride,
             const unsigned short* __restrict__ W0, const unsigned short* __restrict__ W1,
             const float* __restrict__ bias, const float* __restrict__ add1,
             const float* __restrict__ add2, float* __restrict__ Cf,
             unsigned short* __restrict__ Cb, size_t Cstride,
             int K, int Nreal, int flipArg, int act){
  constexpr int BM = WM*FM*16;
  constexpr int BN = WN*FN*16;
  constexpr int NG = (BM+BN)/16;
  constexpr int L  = NG/NW;
  static_assert(NG % NW == 0, "staging must be uniform per wave");
  constexpr int BUFS = (BM+BN)*32;
  __shared__ __align__(16) unsigned short S[NBUF*BUFS];
  int tid = threadIdx.x;
  int w = tid >> 6, lane = tid & 63;
  int gx = gridDim.x;
  int nwg = gx*gridDim.y;
  int bid = blockIdx.x + gx*blockIdx.y;
  int swz = (bid & 7)*(nwg >> 3) + (bid >> 3);
  int n0 = (swz % gx)*BN, m0 = (swz / gx)*BM;
  int dir = blockIdx.z;
  const unsigned short* Aa = A + (size_t)dir*Astride;
  const unsigned short* Wd = dir ? W1 : W0;
  int flip = (flipArg < 0) ? dir : flipArg;
  int wr = w / WN, wc = w % WN;

  f32x4 acc[FM][FN];
#pragma unroll
  for (int i = 0; i < FM; i++)
#pragma unroll
    for (int j = 0; j < FN; j++)
#pragma unroll
      for (int r = 0; r < 4; r++) acc[i][j][r] = 0.f;

  const unsigned short* gp[L];
  int gdst[L];
#pragma unroll
  for (int gi = 0; gi < L; gi++){
    int g = w + gi*NW;
    int r16 = lane >> 2, cch = lane & 3;
    int r = g*16 + r16;
    const unsigned short* src;
    if (r < BM){
      int gm = m0 + r;
      if (flip) gm = (gm & ~(SEQ-1)) | ((SEQ-1) - (gm & (SEQ-1)));
      src = Aa + (size_t)gm*K;
    } else {
      src = Wd + (size_t)(n0 + (r - BM))*K;
    }
    int c2 = (cch + ((r16 >> 1) & 3)) & 3;   // rotated source chunk
    gp[gi] = src + c2*8;
    gdst[gi] = g*16*32;                       // shorts (linear dest)
  }
  int aoff[FM], boff[FN];
#pragma unroll
  for (int i = 0; i < FM; i++){
    int R = wr*FM*16 + i*16 + (lane & 15);
    int slot = ((lane >> 4) - ((R >> 1) & 3)) & 3;
    aoff[i] = R*32 + slot*8;
  }
#pragma unroll
  for (int j = 0; j < FN; j++){
    int R = BM + wc*FN*16 + j*16 + (lane & 15);
    int slot = ((lane >> 4) - ((R >> 1) & 3)) & 3;
    boff[j] = R*32 + slot*8;
  }

  int T = K >> 5;
#pragma unroll
  for (int jt = 0; jt < DEPTH; jt++){
#pragma unroll
    for (int gi = 0; gi < L; gi++)
      __builtin_amdgcn_global_load_lds(
        (const __attribute__((address_space(1))) void*)(gp[gi] + (jt << 5)),
        (__attribute__((address_space(3))) void*)&S[jt*BUFS + gdst[gi]], 16, 0, 0);
  }

  int cs = 0;
  for (int t = 0; t < T; t++){
    int rem = T - 1 - t;
    if (rem >= DEPTH-1)             s_wait_vmcnt<L*(DEPTH-1)>();
    else if constexpr (DEPTH >= 3){ if (rem == 1) s_wait_vmcnt<L>(); else s_wait_vmcnt<0>(); }
    else                            s_wait_vmcnt<0>();
    __builtin_amdgcn_s_barrier();
    __builtin_amdgcn_sched_barrier(0);
    const unsigned short* buf = &S[cs*BUFS];
    bf16x8 af[FM], bfr[FN];
#pragma unroll
    for (int i = 0; i < FM; i++) af[i] = *(const bf16x8*)&buf[aoff[i]];
#pragma unroll
    for (int j = 0; j < FN; j++) bfr[j] = *(const bf16x8*)&buf[boff[j]];
    if constexpr (NBUF == DEPTH){
      asm volatile("s_waitcnt lgkmcnt(0)" ::: "memory");
      __builtin_amdgcn_sched_barrier(0);
      __builtin_amdgcn_s_barrier();
    }
    if (t + DEPTH < T){
      int ss = cs + DEPTH; if (ss >= NBUF) ss -= NBUF;
#pragma unroll
      for (int gi = 0; gi < L; gi++)
        __builtin_amdgcn_global_load_lds(
          (const __attribute__((address_space(1))) void*)(gp[gi] + ((t + DEPTH) << 5)),
          (__attribute__((address_space(3))) void*)&S[ss*BUFS + gdst[gi]], 16, 0, 0);
    }
#pragma unroll
    for (int i = 0; i < FM; i++)
#pragma unroll
      for (int j = 0; j < FN; j++)
        acc[i][j] = __builtin_amdgcn_mfma_f32_16x16x32_bf16(af[i], bfr[j], acc[i][j], 0, 0, 0);
    cs = (cs + 1 == NBUF) ? 0 : cs + 1;
  }

  float* Cfd = Cf ? Cf + (size_t)dir*Cstride : nullptr;
  unsigned short* Cbd = Cb ? Cb + (size_t)dir*Cstride : nullptr;

  if (Cbd){
    // LDS-staged coalesced bf16 epilogue (tiles fully in-bounds; Nreal % BN == 0)
    __syncthreads();
#pragma unroll
    for (int i = 0; i < FM; i++){
#pragma unroll
      for (int j = 0; j < FN; j++){
        int col = wc*FN*16 + j*16 + (lane & 15);
        float bv = bias ? bias[n0 + col] : 0.f;
#pragma unroll
        for (int r = 0; r < 4; r++){
          int row = wr*FM*16 + i*16 + (lane >> 4)*4 + r;
          float x = acc[i][j][r] + bv;
          if (act) x = x*sigf(x);
          S[row*BN + (col ^ ((row & 3) << 3))] = f2bf(x);
        }
      }
    }
    __syncthreads();
    constexpr int TOT8 = BM*BN/8;
    for (int s = tid; s < TOT8; s += NW*64){
      int idx = s*8;
      int row = idx / BN, col = idx % BN;
      u16x8 v = *(const u16x8*)&S[row*BN + (col ^ ((row & 3) << 3))];
      *(u16x8*)&Cbd[(size_t)(m0 + row)*Nreal + n0 + col] = v;
    }
    return;
  }

  int mbase = m0 + wr*FM*16 + (lane >> 4)*4;
  int nbase = n0 + wc*FN*16 + (lane & 15);
#pragma unroll
  for (int i = 0; i < FM; i++){
#pragma unroll
    for (int j = 0; j < FN; j++){
      int col = nbase + j*16;
      if (col < Nreal){
        float bv = bias ? bias[col] : 0.f;
#pragma unroll
        for (int r = 0; r < 4; r++){
          size_t idx = (size_t)(mbase + i*16 + r)*Nreal + col;
          float x = acc[i][j][r] + bv;
          if (act) x = x*sigf(x);
          if (add1) x += add1[idx] + add2[idx];
          Cfd[idx] = x;
        }
      }
    }
  }
}

// ---------------- B/C conv + dt/dA only (x-conv fused into scanA) ----------------
__global__ __launch_bounds__(128)
void convbc_dt_k(const unsigned short* __restrict__ zxb,
                 const float* __restrict__ convw0, const float* __restrict__ convw1,
                 const float* __restrict__ convb0, const float* __restrict__ convb1,
                 const float* __restrict__ dtbias0, const float* __restrict__ dtbias1,
                 const float* __restrict__ Alog0, const float* __restrict__ Alog1,
                 float* __restrict__ Bm, float* __restrict__ Cm,
                 float* __restrict__ dtv, float* __restrict__ dAv){
  int dir = blockIdx.y;
  const unsigned short* zb = zxb + (size_t)dir*ZXBN;
  int r0 = blockIdx.x*4;
  int l0 = r0 & (SEQ-1);
  int rbase = r0 - l0;
  int tid = threadIdx.x;
  if (tid < 32){
    const float* convw = dir ? convw1 : convw0;
    const float* convb = dir ? convb1 : convb0;
    int cc = 1024 + tid;
    int col = 2048 + tid;
    float w0 = convw[cc*4+0], w1 = convw[cc*4+1], w2 = convw[cc*4+2], w3 = convw[cc*4+3];
    float bv = convb[cc];
    float v[7];
#pragma unroll
    for (int i = 0; i < 7; i++){
      int ls = l0 - 3 + i;
      v[i] = (ls >= 0) ? bf2f(zb[(size_t)(rbase+ls)*ZXW + col]) : 0.f;
    }
#pragma unroll
    for (int j = 0; j < 4; j++){
      float acc = bv + v[j]*w0 + v[j+1]*w1 + v[j+2]*w2 + v[j+3]*w3;
      float val = acc*sigf(acc);
      int r = r0 + j;
      if (tid < 16) Bm[(size_t)dir*BCN + (size_t)r*DSTATE + tid] = val;
      else          Cm[(size_t)dir*BCN + (size_t)r*DSTATE + (tid-16)] = val;
    }
  } else if (tid >= 64){
    const float* dtbias = dir ? dtbias1 : dtbias0;
    const float* Alog   = dir ? Alog1 : Alog0;
    int i = tid - 64;
    int j = i >> 4, hh = i & 15;
    int r = r0 + j;
    float x = bf2f(zb[(size_t)r*ZXW + 2080 + hh]) + dtbias[hh];
    float sp = (x > 20.f) ? x : log1pf(expf(x));
    dtv[(size_t)dir*DTN + (size_t)r*NH + hh] = sp;
    dAv[(size_t)dir*DTN + (size_t)r*NH + hh] = expf(-expf(Alog[hh])*sp);
  }
}

// ================= chunked selective scan (NCH=32, CT=64), x-conv fused =================
// scanA: per-chunk local scan + fused x-conv + D*x; B/C/dt/dA read via wave-uniform
// global loads (scalar s_load path) -- no LDS staging, no __syncthreads.
__global__ __launch_bounds__(64)
void scanA_k(const unsigned short* __restrict__ zxb, const float* __restrict__ Bm,
             const float* __restrict__ Cm, const float* __restrict__ dtv,
             const float* __restrict__ dAv,
             const float* __restrict__ convw0, const float* __restrict__ convw1,
             const float* __restrict__ convb0, const float* __restrict__ convb1,
             const float* __restrict__ Dp0, const float* __restrict__ Dp1,
             unsigned short* __restrict__ y,
             float* __restrict__ Hs, float* __restrict__ Ps){
  int gb = blockIdx.x;
  int dir = gb >> 10;
  int idx = gb & 1023;
  int c = idx & (NCH-1);
  int h = (idx >> 5) & 15;
  int b = idx >> 9;
  int p = threadIdx.x;
  int t0 = c*CT;
  const unsigned short* zb = zxb + (size_t)dir*ZXBN;
  const unsigned short* zcol = zb + ((size_t)b*SEQ)*ZXW + 1024 + h*HD + p;
  unsigned short* yb = y + (size_t)dir*YN + ((size_t)b*SEQ + t0)*DIN + h*HD;
  const float* Bb  = Bm + (size_t)dir*BCN + ((size_t)b*SEQ + t0)*DSTATE;
  const float* Cb  = Cm + (size_t)dir*BCN + ((size_t)b*SEQ + t0)*DSTATE;
  const float* dtb = dtv + (size_t)dir*DTN + ((size_t)b*SEQ + t0)*NH + h;
  const float* dAb = dAv + (size_t)dir*DTN + ((size_t)b*SEQ + t0)*NH + h;
  const float* convw = dir ? convw1 : convw0;
  const float* convb = dir ? convb1 : convb0;
  float Dv = (dir ? Dp1 : Dp0)[h];
  int ch = h*HD + p;
  float cw0 = convw[ch*4+0], cw1 = convw[ch*4+1], cw2 = convw[ch*4+2], cw3 = convw[ch*4+3];
  float cbv = convb[ch];

  float hst[16];
#pragma unroll
  for (int n = 0; n < 16; n++) hst[n] = 0.f;
  float P = 1.f;
  float carry0 = (t0 >= 3) ? bf2f(zcol[(size_t)(t0-3)*ZXW]) : 0.f;
  float carry1 = (t0 >= 2) ? bf2f(zcol[(size_t)(t0-2)*ZXW]) : 0.f;
  float carry2 = (t0 >= 1) ? bf2f(zcol[(size_t)(t0-1)*ZXW]) : 0.f;
  float cur[16], nxt[16];
#pragma unroll
  for (int j = 0; j < 16; j++) cur[j] = bf2f(zcol[(size_t)(t0+j)*ZXW]);

  for (int tt = 0; tt < CT; tt += 16){
    bool pf = (tt + 16 < CT);
    if (pf){
#pragma unroll
      for (int j = 0; j < 16; j++) nxt[j] = bf2f(zcol[(size_t)(t0+tt+16+j)*ZXW]);
    }
    float win[19];
    win[0] = carry0; win[1] = carry1; win[2] = carry2;
#pragma unroll
    for (int j = 0; j < 16; j++) win[3+j] = cur[j];
#pragma unroll
    for (int j = 0; j < 16; j++){
      int t = tt + j;
      float xo = cbv + win[j]*cw0 + win[j+1]*cw1 + win[j+2]*cw2 + win[j+3]*cw3;
      float xsil = xo*sigf(xo);
      // wave-uniform loads (scalar path): dt, dA, B, C
      float dtt = dtb[(size_t)t*NH];
      float dA  = dAb[(size_t)t*NH];
      float xv = xsil*dtt;
      P *= dA;
      float4 b0 = *(const float4*)&Bb[(size_t)t*DSTATE + 0];
      float4 b1 = *(const float4*)&Bb[(size_t)t*DSTATE + 4];
      float4 b2 = *(const float4*)&Bb[(size_t)t*DSTATE + 8];
      float4 b3 = *(const float4*)&Bb[(size_t)t*DSTATE + 12];
      hst[0]  = fmaf(dA, hst[0],  b0.x*xv);
      hst[1]  = fmaf(dA, hst[1],  b0.y*xv);
      hst[2]  = fmaf(dA, hst[2],  b0.z*xv);
      hst[3]  = fmaf(dA, hst[3],  b0.w*xv);
      hst[4]  = fmaf(dA, hst[4],  b1.x*xv);
      hst[5]  = fmaf(dA, hst[5],  b1.y*xv);
      hst[6]  = fmaf(dA, hst[6],  b1.z*xv);
      hst[7]  = fmaf(dA, hst[7],  b1.w*xv);
      hst[8]  = fmaf(dA, hst[8],  b2.x*xv);
      hst[9]  = fmaf(dA, hst[9],  b2.y*xv);
      hst[10] = fmaf(dA, hst[10], b2.z*xv);
      hst[11] = fmaf(dA, hst[11], b2.w*xv);
      hst[12] = fmaf(dA, hst[12], b3.x*xv);
      hst[13] = fmaf(dA, hst[13], b3.y*xv);
      hst[14] = fmaf(dA, hst[14], b3.z*xv);
      hst[15] = fmaf(dA, hst[15], b3.w*xv);
      float4 c0 = *(const float4*)&Cb[(size_t)t*DSTATE + 0];
      float4 c1 = *(const float4*)&Cb[(size_t)t*DSTATE + 4];
      float4 c2 = *(const float4*)&Cb[(size_t)t*DSTATE + 8];
      float4 c3 = *(const float4*)&Cb[(size_t)t*DSTATE + 12];
      float a0 = hst[0]*c0.x;  a0 = fmaf(hst[1],  c0.y, a0);
      a0 = fmaf(hst[2],  c0.z, a0); a0 = fmaf(hst[3],  c0.w, a0);
      float a1 = hst[4]*c1.x;  a1 = fmaf(hst[5],  c1.y, a1);
      a1 = fmaf(hst[6],  c1.z, a1); a1 = fmaf(hst[7],  c1.w, a1);
      float a2 = hst[8]*c2.x;  a2 = fmaf(hst[9],  c2.y, a2);
      a2 = fmaf(hst[10], c2.z, a2); a2 = fmaf(hst[11], c2.w, a2);
      float a3 = hst[12]*c3.x; a3 = fmaf(hst[13], c3.y, a3);
      a3 = fmaf(hst[14], c3.z, a3); a3 = fmaf(hst[15], c3.w, a3);
      float dot = (a0+a1)+(a2+a3);
      yb[(size_t)t*DIN + p] = f2bf(dot + Dv*xsil);
    }
    carry0 = cur[13]; carry1 = cur[14]; carry2 = cur[15];
    if (pf){
#pragma unroll
      for (int j = 0; j < 16; j++) cur[j] = nxt[j];
    }
  }
  size_t base = (size_t)dir*HSN + ((size_t)((b*NH + h)*NCH + c))*1024;
#pragma unroll
  for (int n = 0; n < 16; n++) Hs[base + n*64 + p] = hst[n];
  if (p == 0) Ps[dir*1024 + (b*NH + h)*NCH + c] = P;
}

// scanC: fold predecessors' (P,H) then y += cumprod(dA) * (C . h_start)
// C/dA via wave-uniform global loads (scalar path); no LDS.
__global__ __launch_bounds__(64)
void scanC_k(const float* __restrict__ Cm, const float* __restrict__ dAv,
             const float* __restrict__ Hs, const float* __restrict__ Ps,
             unsigned short* __restrict__ y){
  int gb = blockIdx.x;
  int dir = gb >> 10;
  int idx = gb & 1023;
  int c = idx & (NCH-1);
  if (c == 0) return;
  int h = (idx >> 5) & 15;
  int b = idx >> 9;
  int p = threadIdx.x;
  int t0 = c*CT;
  int bh = b*NH + h;
  float hstart[16];
#pragma unroll
  for (int n = 0; n < 16; n++) hstart[n] = 0.f;
  for (int j = 0; j < c; j++){
    float Pj = Ps[dir*1024 + bh*NCH + j];
    const float* Hj = Hs + (size_t)dir*HSN + ((size_t)(bh*NCH + j))*1024;
#pragma unroll
    for (int n = 0; n < 16; n++) hstart[n] = fmaf(Pj, hstart[n], Hj[n*64 + p]);
  }
  const float* Cb  = Cm + (size_t)dir*BCN + ((size_t)b*SEQ + t0)*DSTATE;
  const float* dAb = dAv + (size_t)dir*DTN + ((size_t)b*SEQ + t0)*NH + h;
  unsigned short* yb = y + (size_t)dir*YN + ((size_t)b*SEQ + t0)*DIN + h*HD;

  float cp = 1.f;
  float ycur[16], ynxt[16];
#pragma unroll
  for (int j = 0; j < 16; j++) ycur[j] = bf2f(yb[(size_t)j*DIN + p]);
  for (int tt = 0; tt < CT; tt += 16){
    bool pf = (tt + 16 < CT);
    if (pf){
#pragma unroll
      for (int j = 0; j < 16; j++) ynxt[j] = bf2f(yb[(size_t)(tt+16+j)*DIN + p]);
    }
#pragma unroll
    for (int j = 0; j < 16; j++){
      int t = tt + j;
      cp *= dAb[(size_t)t*NH];
      float4 c0 = *(const float4*)&Cb[(size_t)t*DSTATE + 0];
      float4 c1 = *(const float4*)&Cb[(size_t)t*DSTATE + 4];
      float4 c2 = *(const float4*)&Cb[(size_t)t*DSTATE + 8];
      float4 c3 = *(const float4*)&Cb[(size_t)t*DSTATE + 12];
      float a0 = hstart[0]*c0.x;  a0 = fmaf(hstart[1],  c0.y, a0);
      a0 = fmaf(hstart[2],  c0.z, a0); a0 = fmaf(hstart[3],  c0.w, a0);
      float a1 = hstart[4]*c1.x;  a1 = fmaf(hstart[5],  c1.y, a1);
      a1 = fmaf(hstart[6],  c1.z, a1); a1 = fmaf(hstart[7],  c1.w, a1);
      float a2 = hstart[8]*c2.x;  a2 = fmaf(hstart[9],  c2.y, a2);
      a2 = fmaf(hstart[10], c2.z, a2); a2 = fmaf(hstart[11], c2.w, a2);
      float a3 = hstart[12]*c3.x; a3 = fmaf(hstart[13], c3.y, a3);
      a3 = fmaf(hstart[14], c3.z, a3); a3 = fmaf(hstart[15], c3.w, a3);
      float dot = (a0+a1)+(a2+a3);
      yb[(size_t)t*DIN + p] = f2bf(ycur[j] + cp*dot);
    }
    if (pf){
#pragma unroll
      for (int j = 0; j < 16; j++) ycur[j] = ynxt[j];
    }
  }
}

// ---------------- y(already incl D*x) * silu(z); rmsnorm(1024); out bf16 ----------------
__global__ __launch_bounds__(256)
void gated_rms_k(const unsigned short* __restrict__ y,
                 const unsigned short* __restrict__ zxb,
                 const float* __restrict__ nw0, const float* __restrict__ nw1,
                 unsigned short* __restrict__ out){
  __shared__ float sbuf[4];
  int r = blockIdx.x;
  int dir = blockIdx.y;
  const float* normw = dir ? nw1 : nw0;
  const unsigned short* yr = y + (size_t)dir*YN + (size_t)r*DIN;
  const unsigned short* zr = zxb + (size_t)dir*ZXBN + (size_t)r*ZXW;
  unsigned short* outr = out + (size_t)dir*((size_t)ROWS*DIN) + (size_t)r*DIN;
  int d0 = threadIdx.x*4;
  ushort4 yu4 = *(const ushort4*)&yr[d0];
  ushort4 zu4 = *(const ushort4*)&zr[d0];
  float vals[4]; float ss = 0.f;
  float yv[4] = {bf2f(yu4.x), bf2f(yu4.y), bf2f(yu4.z), bf2f(yu4.w)};
  float zv[4] = {bf2f(zu4.x), bf2f(zu4.y), bf2f(zu4.z), bf2f(zu4.w)};
#pragma unroll
  for (int i = 0; i < 4; i++){
    float g = yv[i] * (zv[i]*sigf(zv[i]));
    vals[i] = g; ss += g*g;
  }
  ss = block_reduce_256(ss, sbuf);
  float rs = rsqrtf(ss*(1.f/DIN) + 1e-5f);
  ushort4 o;
  o.x = f2bf(normw[d0+0]*vals[0]*rs);
  o.y = f2bf(normw[d0+1]*vals[1]*rs);
  o.z = f2bf(normw[d0+2]*vals[2]*rs);
  o.w = f2bf(normw[d0+3]*vals[3]*rs);
  *(ushort4*)&outr[d0] = o;
}

// ---------------- hsum = outf + flip(outb) + hid; h2_bf = rmsnorm(hsum) ----------------
__global__ __launch_bounds__(256)
void addres_rms_k(const float* __restrict__ outf, const float* __restrict__ outb,
                  const float* __restrict__ hid, const float* __restrict__ w,
                  float* __restrict__ hsum, unsigned short* __restrict__ h2b){
  __shared__ float sbuf[4];
  int r = blockIdx.x;
  int l = r & (SEQ-1);
  int rb = (r - l) + ((SEQ-1) - l);
  float vals[2]; float ss = 0.f;
#pragma unroll
  for (int i = 0; i < 2; i++){
    int d = threadIdx.x + i*256;
    float v = outf[(size_t)r*DM + d] + outb[(size_t)rb*DM + d] + hid[(size_t)r*DM + d];
    hsum[(size_t)r*DM + d] = v;
    vals[i] = v; ss += v*v;
  }
  ss = block_reduce_256(ss, sbuf);
  float rs = rsqrtf(ss*(1.f/DM) + 1e-6f);
#pragma unroll
  for (int i = 0; i < 2; i++){
    int d = threadIdx.x + i*256;
    h2b[(size_t)r*DM + d] = f2bf(w[d]*vals[i]*rs);
  }
}

extern "C" void kernel_launch(void* const* d_in, const int* in_sizes, int n_in,
                              void* d_out, int out_size, void* d_ws, size_t ws_size,
                              hipStream_t stream){
  const float* hid     = (const float*)d_in[0];
  const float* norm1_w = (const float*)d_in[1];
  const float* wfc_w   = (const float*)d_in[2];
  const float* wfc_b   = (const float*)d_in[3];
  const float* gfc_w   = (const float*)d_in[4];
  const float* gfc_b   = (const float*)d_in[5];
  const float* norm2_w = (const float*)d_in[6];
  const float* fc1_w   = (const float*)d_in[7];
  const float* fc1_b   = (const float*)d_in[8];
  const float* fc2_w   = (const float*)d_in[9];
  const float* fc2_b   = (const float*)d_in[10];
  const float* inproj[2]  = {(const float*)d_in[11], (const float*)d_in[19]};
  const float* convw[2]   = {(const float*)d_in[12], (const float*)d_in[20]};
  const float* convb[2]   = {(const float*)d_in[13], (const float*)d_in[21]};
  const float* dtbias[2]  = {(const float*)d_in[14], (const float*)d_in[22]};
  const float* Alog[2]    = {(const float*)d_in[15], (const float*)d_in[23]};
  const float* Dp[2]      = {(const float*)d_in[16], (const float*)d_in[24]};
  const float* normw[2]   = {(const float*)d_in[17], (const float*)d_in[25]};
  const float* outproj[2] = {(const float*)d_in[18], (const float*)d_in[26]};

  float* ws = (float*)d_ws;
  unsigned short* zxb = (unsigned short*)ws;          // 2 x 4096x2176 bf16 = 8,912,896 f
  float* Bmb   = ws + 8912896;              // 131,072 f
  float* Cmb   = Bmb + 2*BCN;               // 131,072 f
  float* dtv   = Cmb + 2*BCN;               // 131,072 f
  float* dAv   = dtv + 2*DTN;               // 131,072 f
  float* ysc   = dAv + 2*DTN;               // ysc bf16: 4,194,304 f, then Ps
  unsigned short* ysc_b = (unsigned short*)ysc;
  float* Ps    = ysc + 4194304;             // 2,048 f
  float* outd  = Ps + 2048;                 // 4,194,304 f (dir-strided 2,097,152)
  float* hsum  = outd + 4194304;            // 2,097,152 f (hosts Hs during scan)
  float* hnorm = hsum + 2097152;            // 2,097,152 f
  unsigned short* hnorm_bf = (unsigned short*)(hnorm + 2097152);           // 1,048,576 f
  unsigned short* ysc_bf   = (unsigned short*)(hnorm + 2097152 + 1048576); // 4,194,304 f
  unsigned short* wbf      = (unsigned short*)(hnorm + 2097152 + 1048576 + 4194304); // 2,686,976 f
  float* Hs = hsum;                          // 2*HSN floats (scan phase only)
  unsigned short* a1_bf = (unsigned short*)zxb;   // zxb free after gated_rms
  unsigned short* h2_bf = (unsigned short*)ysc;   // ysc free after gated_rms
  unsigned short* wi0 = wbf,            * wi1 = wbf + 1114112;   // 2176x512 each
  unsigned short* wo0 = wbf + 2228224,  * wo1 = wbf + 2752512;   // 512x1024 each
  unsigned short* wf1 = wbf + 3276800;                            // 2048x512
  unsigned short* wf2 = wbf + 4325376;                            // 512x2048
  size_t need_bytes = (size_t)29952000*4;
  if (ws_size < need_bytes) return;

  // weight casts: inproj padded to 2176, rest flat
  castpad2_k<<<(2*2176*512)/256, 256, 0, stream>>>(inproj[0], inproj[1], wi0, wi1, 2096, 512, 2176);
  Cast6 cp;
  cp.src[0] = outproj[0]; cp.dst[0] = wo0; cp.n[0] = 512*1024;
  cp.src[1] = outproj[1]; cp.dst[1] = wo1; cp.n[1] = 512*1024;
  cp.src[2] = fc1_w; cp.dst[2] = wf1; cp.n[2] = 2048*512;
  cp.src[3] = fc2_w; cp.dst[3] = wf2; cp.n[3] = 512*2048;
  cp.src[4] = fc2_w; cp.dst[4] = wf2; cp.n[4] = 0;
  cp.src[5] = fc2_w; cp.dst[5] = wf2; cp.n[5] = 0;
  cast6_k<<<dim3((2048*512/4)/256, 4), 256, 0, stream>>>(cp);

  rmsnorm512_k<<<ROWS, 256, 0, stream>>>(hid, norm1_w, hnorm, hnorm_bf, 1e-6f);
  gated_fusion_k<<<BSZ*(SEQ/16), 256, 0, stream>>>(hnorm, hnorm_bf, wfc_w, wfc_b, gfc_w, gfc_b);

  // inproj both dirs: 4096x2176x512, 8-wave 128x128, DEPTH=2/NBUF=2
  mgemm_k<8,2,4,4,2,2,2><<<dim3(2176/128, 4096/128, 2), 512, 0, stream>>>(
      hnorm_bf, 0, wi0, wi1, nullptr, nullptr, nullptr, nullptr, zxb, ZXBN,
      512, ZXW, -1, 0);
  convbc_dt_k<<<dim3(ROWS/4, 2), 128, 0, stream>>>(
      zxb, convw[0], convw[1], convb[0], convb[1], dtbias[0], dtbias[1],
      Alog[0], Alog[1], Bmb, Cmb, dtv, dAv);
  scanA_k<<<2*BSZ*NH*NCH, 64, 0, stream>>>(
      zxb, Bmb, Cmb, dtv, dAv, convw[0], convw[1], convb[0], convb[1],
      Dp[0], Dp[1], ysc_b, Hs, Ps);
  scanC_k<<<2*BSZ*NH*NCH, 64, 0, stream>>>(Cmb, dAv, Hs, Ps, ysc_b);
  gated_rms_k<<<dim3(ROWS, 2), 256, 0, stream>>>(
      ysc_b, zxb, normw[0], normw[1], ysc_bf);
  // outproj both dirs: 64x64 tile, depth-3/4buf
  mgemm_k<8,2,4,2,1,3,4><<<dim3(512/64, 4096/64, 2), 512, 0, stream>>>(
      ysc_bf, (size_t)ROWS*DIN, wo0, wo1, nullptr, nullptr, nullptr,
      outd, nullptr, 2097152, 1024, DM, 0, 0);

  addres_rms_k<<<ROWS, 256, 0, stream>>>(outd, outd + 2097152, hid, norm2_w, hsum, h2_bf);
  mgemm_k<8,2,4,4,2,3,3><<<dim3(2048/128, 4096/128, 1), 512, 0, stream>>>(
      h2_bf, 0, wf1, wf1, fc1_b, nullptr, nullptr, nullptr, a1_bf, 0,
      512, DFF, 0, 1);
  mgemm_k<8,2,4,2,1,3,4><<<dim3(512/64, 4096/64, 1), 512, 0, stream>>>(
      a1_bf, 0, wf2, wf2, fc2_b, hsum, hid, (float*)d_out, nullptr, 0,
      2048, DM, 0, 0);
}

// Round 23
// 195.264 us; speedup vs baseline: 1.1404x; 1.1404x over previous
//
#include <hip/hip_runtime.h>
#include <math.h>

#define SEQ 2048
#define BSZ 2
#define DM 512
#define DIN 1024
#define DSTATE 16
#define NH 16
#define HD 64
#define CONVDIM 1056
#define DINPROJ 2096
#define DFF 2048
#define ROWS (BSZ*SEQ)
#define NCH 32
#define CT  (SEQ/NCH)     // 64
#define ZXW 2176          // padded zx row width (bf16)
// per-direction strides (element counts)
#define ZXBN 8912896ull   // shorts: 4096 x 2176 bf16
#define BCN 65536ull
#define DTN 65536ull
#define YN  4194304ull    // shorts (bf16 scan y, includes D*x)
#define HSN 1048576ull    // floats: per-dir chunk summaries (32bh x 32ch x 1024)

typedef short bf16x8 __attribute__((ext_vector_type(8)));
typedef float f32x4  __attribute__((ext_vector_type(4)));
typedef unsigned short u16x8 __attribute__((ext_vector_type(8)));

__device__ __forceinline__ float sigf(float x){ return 1.f/(1.f+expf(-x)); }

__device__ __forceinline__ unsigned short f2bf(float f){
  union { float f; unsigned u; } v; v.f = f;
  unsigned r = (v.u + 0x7FFFu + ((v.u >> 16) & 1u)) >> 16;
  return (unsigned short)r;
}
__device__ __forceinline__ float bf2f(unsigned short h){
  union { unsigned u; float f; } v; v.u = ((unsigned)h) << 16;
  return v.f;
}

template<int N> __device__ __forceinline__ void s_wait_vmcnt(){
  if constexpr (N == 0)      asm volatile("s_waitcnt vmcnt(0)" ::: "memory");
  else if constexpr (N == 1) asm volatile("s_waitcnt vmcnt(1)" ::: "memory");
  else if constexpr (N == 2) asm volatile("s_waitcnt vmcnt(2)" ::: "memory");
  else if constexpr (N == 3) asm volatile("s_waitcnt vmcnt(3)" ::: "memory");
  else if constexpr (N == 4) asm volatile("s_waitcnt vmcnt(4)" ::: "memory");
  else                       asm volatile("s_waitcnt vmcnt(8)" ::: "memory");
}

__device__ __forceinline__ float wave_reduce(float v){
#pragma unroll
  for (int o = 32; o > 0; o >>= 1) v += __shfl_down(v, o);
  return v;
}

__device__ __forceinline__ float block_reduce_256(float v, float* sbuf){
  v = wave_reduce(v);
  int lane = threadIdx.x & 63, wid = threadIdx.x >> 6;
  if (lane == 0) sbuf[wid] = v;
  __syncthreads();
  float s = sbuf[0] + sbuf[1] + sbuf[2] + sbuf[3];
  __syncthreads();
  return s;
}

// ---------------- weight cast + N-pad to bf16 (inproj pair) ----------------
__global__ __launch_bounds__(256)
void castpad2_k(const float* __restrict__ in0, const float* __restrict__ in1,
                unsigned short* __restrict__ out0, unsigned short* __restrict__ out1,
                int N, int K, int Npad){
  int tot = Npad*K;
  int idx = blockIdx.x*256 + threadIdx.x;
  const float* in = in0; unsigned short* out = out0;
  if (idx >= tot){ idx -= tot; in = in1; out = out1; }
  if (idx >= tot) return;
  int n = idx / K, k = idx - n*K;
  out[idx] = (n < N) ? f2bf(in[(size_t)n*K + k]) : (unsigned short)0;
}

// ---------------- flat weight casts (4 segments) ----------------
struct Cast6 {
  const float* src[6];
  unsigned short* dst[6];
  int n[6];
};
__global__ __launch_bounds__(256)
void cast6_k(Cast6 cp){
  int seg = blockIdx.y;
  int n4 = cp.n[seg] >> 2;
  int i = blockIdx.x*256 + threadIdx.x;
  if (i >= n4) return;
  const float* src = cp.src[seg];
  unsigned short* dst = cp.dst[seg];
  float4 v = *(const float4*)&src[i*4];
  ushort4 o;
  o.x = f2bf(v.x); o.y = f2bf(v.y); o.z = f2bf(v.z); o.w = f2bf(v.w);
  *(ushort4*)&dst[i*4] = o;
}

// ---------------- rmsnorm over D=512, writes fp32 + bf16 ----------------
__global__ __launch_bounds__(256)
void rmsnorm512_k(const float* __restrict__ x, const float* __restrict__ w,
                  float* __restrict__ y, unsigned short* __restrict__ yb, float eps){
  __shared__ float sbuf[4];
  int r = blockIdx.x;
  const float* xr = x + (size_t)r*DM;
  float v0 = xr[threadIdx.x];
  float v1 = xr[threadIdx.x + 256];
  float ss = block_reduce_256(v0*v0 + v1*v1, sbuf);
  float rs = rsqrtf(ss*(1.f/DM) + eps);
  float o0 = w[threadIdx.x]*v0*rs;
  float o1 = w[threadIdx.x+256]*v1*rs;
  y[(size_t)r*DM + threadIdx.x]       = o0;
  y[(size_t)r*DM + threadIdx.x + 256] = o1;
  yb[(size_t)r*DM + threadIdx.x]       = f2bf(o0);
  yb[(size_t)r*DM + threadIdx.x + 256] = f2bf(o1);
}

// ---------------- gated fusion (query rows, updates fp32 + bf16) ----------------
__global__ __launch_bounds__(256)
void gated_fusion_k(float* __restrict__ h, unsigned short* __restrict__ hb,
                    const float* __restrict__ wfc_w, const float* __restrict__ wfc_b,
                    const float* __restrict__ gfc_w, const float* __restrict__ gfc_b){
  int c = blockIdx.x;
  float* base = h + (size_t)c*16*DM;
  float* qrow = base + 15*DM;
  unsigned short* qrow_b = hb + (size_t)c*16*DM + 15*DM;
  __shared__ float q[DM];
  __shared__ float dots[16];
  for (int i = threadIdx.x; i < DM; i += 256) q[i] = qrow[i];
  __syncthreads();
  int wid = threadIdx.x >> 6, lane = threadIdx.x & 63;
  for (int f = wid; f < 16; f += 4){
    const float* wf = (f < 15) ? (wfc_w + (size_t)f*DM) : gfc_w;
    float s = 0.f;
    for (int i = lane; i < DM; i += 64) s += q[i]*wf[i];
    s = wave_reduce(s);
    if (lane == 0) dots[f] = s;
  }
  __syncthreads();
  if (threadIdx.x == 0){
    float mx = -1e30f;
    for (int f = 0; f < 15; f++){ dots[f] += wfc_b[f]; mx = fmaxf(mx, dots[f]); }
    float sum = 0.f;
    for (int f = 0; f < 15; f++){ float e = expf(dots[f]-mx); dots[f] = e; sum += e; }
    float inv = 1.f/sum;
    for (int f = 0; f < 15; f++) dots[f] *= inv;
    float g = sigf(dots[15] + gfc_b[0]);
    dots[15] = g*0.98f + 0.01f;
  }
  __syncthreads();
  float gate = dots[15];
  for (int d = threadIdx.x; d < DM; d += 256){
    float agg = 0.f;
#pragma unroll
    for (int f = 0; f < 15; f++) agg += base[(size_t)f*DM + d]*dots[f];
    float qn = q[d]*(1.f-gate) + agg*gate;
    qrow[d] = qn;
    qrow_b[d] = f2bf(qn);
  }
}

// ---------------- MFMA bf16 GEMM, counted-vmcnt pipeline + XCD swizzle ----------------
template<int NW, int WM, int WN, int FM, int FN, int DEPTH, int NBUF>
__global__ __launch_bounds__(NW*64)
void mgemm_k(const unsigned short* __restrict__ A, size_t Astride,
             const unsigned short* __restrict__ W0, const unsigned short* __restrict__ W1,
             const float* __restrict__ bias, const float* __restrict__ add1,
             const float* __restrict__ add2, float* __restrict__ Cf,
             unsigned short* __restrict__ Cb, size_t Cstride,
             int K, int Nreal, int flipArg, int act){
  constexpr int BM = WM*FM*16;
  constexpr int BN = WN*FN*16;
  constexpr int NG = (BM+BN)/16;
  constexpr int L  = NG/NW;
  static_assert(NG % NW == 0, "staging must be uniform per wave");
  constexpr int BUFS = (BM+BN)*32;
  __shared__ __align__(16) unsigned short S[NBUF*BUFS];
  int tid = threadIdx.x;
  int w = tid >> 6, lane = tid & 63;
  int gx = gridDim.x;
  int nwg = gx*gridDim.y;
  int bid = blockIdx.x + gx*blockIdx.y;
  int swz = (bid & 7)*(nwg >> 3) + (bid >> 3);
  int n0 = (swz % gx)*BN, m0 = (swz / gx)*BM;
  int dir = blockIdx.z;
  const unsigned short* Aa = A + (size_t)dir*Astride;
  const unsigned short* Wd = dir ? W1 : W0;
  int flip = (flipArg < 0) ? dir : flipArg;
  int wr = w / WN, wc = w % WN;

  f32x4 acc[FM][FN];
#pragma unroll
  for (int i = 0; i < FM; i++)
#pragma unroll
    for (int j = 0; j < FN; j++)
#pragma unroll
      for (int r = 0; r < 4; r++) acc[i][j][r] = 0.f;

  const unsigned short* gp[L];
  int gdst[L];
#pragma unroll
  for (int gi = 0; gi < L; gi++){
    int g = w + gi*NW;
    int r16 = lane >> 2, cch = lane & 3;
    int r = g*16 + r16;
    const unsigned short* src;
    if (r < BM){
      int gm = m0 + r;
      if (flip) gm = (gm & ~(SEQ-1)) | ((SEQ-1) - (gm & (SEQ-1)));
      src = Aa + (size_t)gm*K;
    } else {
      src = Wd + (size_t)(n0 + (r - BM))*K;
    }
    int c2 = (cch + ((r16 >> 1) & 3)) & 3;   // rotated source chunk
    gp[gi] = src + c2*8;
    gdst[gi] = g*16*32;                       // shorts (linear dest)
  }
  int aoff[FM], boff[FN];
#pragma unroll
  for (int i = 0; i < FM; i++){
    int R = wr*FM*16 + i*16 + (lane & 15);
    int slot = ((lane >> 4) - ((R >> 1) & 3)) & 3;
    aoff[i] = R*32 + slot*8;
  }
#pragma unroll
  for (int j = 0; j < FN; j++){
    int R = BM + wc*FN*16 + j*16 + (lane & 15);
    int slot = ((lane >> 4) - ((R >> 1) & 3)) & 3;
    boff[j] = R*32 + slot*8;
  }

  int T = K >> 5;
#pragma unroll
  for (int jt = 0; jt < DEPTH; jt++){
#pragma unroll
    for (int gi = 0; gi < L; gi++)
      __builtin_amdgcn_global_load_lds(
        (const __attribute__((address_space(1))) void*)(gp[gi] + (jt << 5)),
        (__attribute__((address_space(3))) void*)&S[jt*BUFS + gdst[gi]], 16, 0, 0);
  }

  int cs = 0;
  for (int t = 0; t < T; t++){
    int rem = T - 1 - t;
    if (rem >= DEPTH-1)             s_wait_vmcnt<L*(DEPTH-1)>();
    else if constexpr (DEPTH >= 3){ if (rem == 1) s_wait_vmcnt<L>(); else s_wait_vmcnt<0>(); }
    else                            s_wait_vmcnt<0>();
    __builtin_amdgcn_s_barrier();
    __builtin_amdgcn_sched_barrier(0);
    const unsigned short* buf = &S[cs*BUFS];
    bf16x8 af[FM], bfr[FN];
#pragma unroll
    for (int i = 0; i < FM; i++) af[i] = *(const bf16x8*)&buf[aoff[i]];
#pragma unroll
    for (int j = 0; j < FN; j++) bfr[j] = *(const bf16x8*)&buf[boff[j]];
    if constexpr (NBUF == DEPTH){
      asm volatile("s_waitcnt lgkmcnt(0)" ::: "memory");
      __builtin_amdgcn_sched_barrier(0);
      __builtin_amdgcn_s_barrier();
    }
    if (t + DEPTH < T){
      int ss = cs + DEPTH; if (ss >= NBUF) ss -= NBUF;
#pragma unroll
      for (int gi = 0; gi < L; gi++)
        __builtin_amdgcn_global_load_lds(
          (const __attribute__((address_space(1))) void*)(gp[gi] + ((t + DEPTH) << 5)),
          (__attribute__((address_space(3))) void*)&S[ss*BUFS + gdst[gi]], 16, 0, 0);
    }
#pragma unroll
    for (int i = 0; i < FM; i++)
#pragma unroll
      for (int j = 0; j < FN; j++)
        acc[i][j] = __builtin_amdgcn_mfma_f32_16x16x32_bf16(af[i], bfr[j], acc[i][j], 0, 0, 0);
    cs = (cs + 1 == NBUF) ? 0 : cs + 1;
  }

  float* Cfd = Cf ? Cf + (size_t)dir*Cstride : nullptr;
  unsigned short* Cbd = Cb ? Cb + (size_t)dir*Cstride : nullptr;

  if (Cbd){
    // LDS-staged coalesced bf16 epilogue (tiles fully in-bounds; Nreal % BN == 0)
    __syncthreads();
#pragma unroll
    for (int i = 0; i < FM; i++){
#pragma unroll
      for (int j = 0; j < FN; j++){
        int col = wc*FN*16 + j*16 + (lane & 15);
        float bv = bias ? bias[n0 + col] : 0.f;
#pragma unroll
        for (int r = 0; r < 4; r++){
          int row = wr*FM*16 + i*16 + (lane >> 4)*4 + r;
          float x = acc[i][j][r] + bv;
          if (act) x = x*sigf(x);
          S[row*BN + (col ^ ((row & 3) << 3))] = f2bf(x);
        }
      }
    }
    __syncthreads();
    constexpr int TOT8 = BM*BN/8;
    for (int s = tid; s < TOT8; s += NW*64){
      int idx = s*8;
      int row = idx / BN, col = idx % BN;
      u16x8 v = *(const u16x8*)&S[row*BN + (col ^ ((row & 3) << 3))];
      *(u16x8*)&Cbd[(size_t)(m0 + row)*Nreal + n0 + col] = v;
    }
    return;
  }

  int mbase = m0 + wr*FM*16 + (lane >> 4)*4;
  int nbase = n0 + wc*FN*16 + (lane & 15);
#pragma unroll
  for (int i = 0; i < FM; i++){
#pragma unroll
    for (int j = 0; j < FN; j++){
      int col = nbase + j*16;
      if (col < Nreal){
        float bv = bias ? bias[col] : 0.f;
#pragma unroll
        for (int r = 0; r < 4; r++){
          size_t idx = (size_t)(mbase + i*16 + r)*Nreal + col;
          float x = acc[i][j][r] + bv;
          if (act) x = x*sigf(x);
          if (add1) x += add1[idx] + add2[idx];
          Cfd[idx] = x;
        }
      }
    }
  }
}

// ---------------- B/C conv + dt/dA only (x-conv fused into scanA) ----------------
__global__ __launch_bounds__(128)
void convbc_dt_k(const unsigned short* __restrict__ zxb,
                 const float* __restrict__ convw0, const float* __restrict__ convw1,
                 const float* __restrict__ convb0, const float* __restrict__ convb1,
                 const float* __restrict__ dtbias0, const float* __restrict__ dtbias1,
                 const float* __restrict__ Alog0, const float* __restrict__ Alog1,
                 float* __restrict__ Bm, float* __restrict__ Cm,
                 float* __restrict__ dtv, float* __restrict__ dAv){
  int dir = blockIdx.y;
  const unsigned short* zb = zxb + (size_t)dir*ZXBN;
  int r0 = blockIdx.x*4;
  int l0 = r0 & (SEQ-1);
  int rbase = r0 - l0;
  int tid = threadIdx.x;
  if (tid < 32){
    const float* convw = dir ? convw1 : convw0;
    const float* convb = dir ? convb1 : convb0;
    int cc = 1024 + tid;
    int col = 2048 + tid;
    float w0 = convw[cc*4+0], w1 = convw[cc*4+1], w2 = convw[cc*4+2], w3 = convw[cc*4+3];
    float bv = convb[cc];
    float v[7];
#pragma unroll
    for (int i = 0; i < 7; i++){
      int ls = l0 - 3 + i;
      v[i] = (ls >= 0) ? bf2f(zb[(size_t)(rbase+ls)*ZXW + col]) : 0.f;
    }
#pragma unroll
    for (int j = 0; j < 4; j++){
      float acc = bv + v[j]*w0 + v[j+1]*w1 + v[j+2]*w2 + v[j+3]*w3;
      float val = acc*sigf(acc);
      int r = r0 + j;
      if (tid < 16) Bm[(size_t)dir*BCN + (size_t)r*DSTATE + tid] = val;
      else          Cm[(size_t)dir*BCN + (size_t)r*DSTATE + (tid-16)] = val;
    }
  } else if (tid >= 64){
    const float* dtbias = dir ? dtbias1 : dtbias0;
    const float* Alog   = dir ? Alog1 : Alog0;
    int i = tid - 64;
    int j = i >> 4, hh = i & 15;
    int r = r0 + j;
    float x = bf2f(zb[(size_t)r*ZXW + 2080 + hh]) + dtbias[hh];
    float sp = (x > 20.f) ? x : log1pf(expf(x));
    dtv[(size_t)dir*DTN + (size_t)r*NH + hh] = sp;
    dAv[(size_t)dir*DTN + (size_t)r*NH + hh] = expf(-expf(Alog[hh])*sp);
  }
}

// ================= chunked selective scan (NCH=32, CT=64), x-conv fused =================
// scanA: per-chunk local scan + fused x-conv + D*x; writes y_local, P_c, H_c.
__global__ __launch_bounds__(64)
void scanA_k(const unsigned short* __restrict__ zxb, const float* __restrict__ Bm,
             const float* __restrict__ Cm, const float* __restrict__ dtv,
             const float* __restrict__ dAv,
             const float* __restrict__ convw0, const float* __restrict__ convw1,
             const float* __restrict__ convb0, const float* __restrict__ convb1,
             const float* __restrict__ Dp0, const float* __restrict__ Dp1,
             unsigned short* __restrict__ y,
             float* __restrict__ Hs, float* __restrict__ Ps){
  int gb = blockIdx.x;
  int dir = gb >> 10;
  int idx = gb & 1023;
  int c = idx & (NCH-1);
  int h = (idx >> 5) & 15;
  int b = idx >> 9;
  int p = threadIdx.x;
  int t0 = c*CT;
  __shared__ __align__(16) float sB[CT][16];
  __shared__ __align__(16) float sC[CT][16];
  __shared__ float sdt[CT];
  __shared__ float sdA[CT];
  const unsigned short* zb = zxb + (size_t)dir*ZXBN;
  const unsigned short* zcol = zb + ((size_t)b*SEQ)*ZXW + 1024 + h*HD + p;
  unsigned short* yb = y + (size_t)dir*YN + ((size_t)b*SEQ + t0)*DIN + h*HD;
  const float* Bb  = Bm + (size_t)dir*BCN + ((size_t)b*SEQ + t0)*DSTATE;
  const float* Cb  = Cm + (size_t)dir*BCN + ((size_t)b*SEQ + t0)*DSTATE;
  const float* dtb = dtv + (size_t)dir*DTN + ((size_t)b*SEQ + t0)*NH + h;
  const float* dAb = dAv + (size_t)dir*DTN + ((size_t)b*SEQ + t0)*NH + h;
  const float* convw = dir ? convw1 : convw0;
  const float* convb = dir ? convb1 : convb0;
  float Dv = (dir ? Dp1 : Dp0)[h];
  int ch = h*HD + p;
  float cw0 = convw[ch*4+0], cw1 = convw[ch*4+1], cw2 = convw[ch*4+2], cw3 = convw[ch*4+3];
  float cbv = convb[ch];
#pragma unroll
  for (int k = 0; k < (CT*16)/64; k++){
    int i = p + k*64;
    ((float*)sB)[i] = Bb[i];
    ((float*)sC)[i] = Cb[i];
  }
  sdt[p] = dtb[(size_t)p*NH];
  sdA[p] = dAb[(size_t)p*NH];
  __syncthreads();

  float hst[16];
#pragma unroll
  for (int n = 0; n < 16; n++) hst[n] = 0.f;
  float P = 1.f;
  float carry0 = (t0 >= 3) ? bf2f(zcol[(size_t)(t0-3)*ZXW]) : 0.f;
  float carry1 = (t0 >= 2) ? bf2f(zcol[(size_t)(t0-2)*ZXW]) : 0.f;
  float carry2 = (t0 >= 1) ? bf2f(zcol[(size_t)(t0-1)*ZXW]) : 0.f;
  float cur[16], nxt[16];
#pragma unroll
  for (int j = 0; j < 16; j++) cur[j] = bf2f(zcol[(size_t)(t0+j)*ZXW]);

  for (int tt = 0; tt < CT; tt += 16){
    bool pf = (tt + 16 < CT);
    if (pf){
#pragma unroll
      for (int j = 0; j < 16; j++) nxt[j] = bf2f(zcol[(size_t)(t0+tt+16+j)*ZXW]);
    }
    float win[19];
    win[0] = carry0; win[1] = carry1; win[2] = carry2;
#pragma unroll
    for (int j = 0; j < 16; j++) win[3+j] = cur[j];
#pragma unroll
    for (int j = 0; j < 16; j++){
      int t = tt + j;
      float xo = cbv + win[j]*cw0 + win[j+1]*cw1 + win[j+2]*cw2 + win[j+3]*cw3;
      float xsil = xo*sigf(xo);
      float xv = xsil*sdt[t];
      float dA = sdA[t];
      P *= dA;
      float4 b0 = *(const float4*)&sB[t][0];
      float4 b1 = *(const float4*)&sB[t][4];
      float4 b2 = *(const float4*)&sB[t][8];
      float4 b3 = *(const float4*)&sB[t][12];
      hst[0]  = fmaf(dA, hst[0],  b0.x*xv);
      hst[1]  = fmaf(dA, hst[1],  b0.y*xv);
      hst[2]  = fmaf(dA, hst[2],  b0.z*xv);
      hst[3]  = fmaf(dA, hst[3],  b0.w*xv);
      hst[4]  = fmaf(dA, hst[4],  b1.x*xv);
      hst[5]  = fmaf(dA, hst[5],  b1.y*xv);
      hst[6]  = fmaf(dA, hst[6],  b1.z*xv);
      hst[7]  = fmaf(dA, hst[7],  b1.w*xv);
      hst[8]  = fmaf(dA, hst[8],  b2.x*xv);
      hst[9]  = fmaf(dA, hst[9],  b2.y*xv);
      hst[10] = fmaf(dA, hst[10], b2.z*xv);
      hst[11] = fmaf(dA, hst[11], b2.w*xv);
      hst[12] = fmaf(dA, hst[12], b3.x*xv);
      hst[13] = fmaf(dA, hst[13], b3.y*xv);
      hst[14] = fmaf(dA, hst[14], b3.z*xv);
      hst[15] = fmaf(dA, hst[15], b3.w*xv);
      float4 c0 = *(const float4*)&sC[t][0];
      float4 c1 = *(const float4*)&sC[t][4];
      float4 c2 = *(const float4*)&sC[t][8];
      float4 c3 = *(const float4*)&sC[t][12];
      float a0 = hst[0]*c0.x;  a0 = fmaf(hst[1],  c0.y, a0);
      a0 = fmaf(hst[2],  c0.z, a0); a0 = fmaf(hst[3],  c0.w, a0);
      float a1 = hst[4]*c1.x;  a1 = fmaf(hst[5],  c1.y, a1);
      a1 = fmaf(hst[6],  c1.z, a1); a1 = fmaf(hst[7],  c1.w, a1);
      float a2 = hst[8]*c2.x;  a2 = fmaf(hst[9],  c2.y, a2);
      a2 = fmaf(hst[10], c2.z, a2); a2 = fmaf(hst[11], c2.w, a2);
      float a3 = hst[12]*c3.x; a3 = fmaf(hst[13], c3.y, a3);
      a3 = fmaf(hst[14], c3.z, a3); a3 = fmaf(hst[15], c3.w, a3);
      float dot = (a0+a1)+(a2+a3);
      yb[(size_t)t*DIN + p] = f2bf(dot + Dv*xsil);
    }
    carry0 = cur[13]; carry1 = cur[14]; carry2 = cur[15];
    if (pf){
#pragma unroll
      for (int j = 0; j < 16; j++) cur[j] = nxt[j];
    }
  }
  size_t base = (size_t)dir*HSN + ((size_t)((b*NH + h)*NCH + c))*1024;
#pragma unroll
  for (int n = 0; n < 16; n++) Hs[base + n*64 + p] = hst[n];
  if (p == 0) Ps[dir*1024 + (b*NH + h)*NCH + c] = P;
}

// scanC: fold predecessors' (P,H) then y += cumprod(dA) * (C . h_start)
__global__ __launch_bounds__(64)
void scanC_k(const float* __restrict__ Cm, const float* __restrict__ dAv,
             const float* __restrict__ Hs, const float* __restrict__ Ps,
             unsigned short* __restrict__ y){
  int gb = blockIdx.x;
  int dir = gb >> 10;
  int idx = gb & 1023;
  int c = idx & (NCH-1);
  if (c == 0) return;
  int h = (idx >> 5) & 15;
  int b = idx >> 9;
  int p = threadIdx.x;
  int t0 = c*CT;
  int bh = b*NH + h;
  float hstart[16];
#pragma unroll
  for (int n = 0; n < 16; n++) hstart[n] = 0.f;
  for (int j = 0; j < c; j++){
    float Pj = Ps[dir*1024 + bh*NCH + j];
    const float* Hj = Hs + (size_t)dir*HSN + ((size_t)(bh*NCH + j))*1024;
#pragma unroll
    for (int n = 0; n < 16; n++) hstart[n] = fmaf(Pj, hstart[n], Hj[n*64 + p]);
  }
  __shared__ __align__(16) float sC[CT][16];
  __shared__ float sdA[CT];
  const float* Cb  = Cm + (size_t)dir*BCN + ((size_t)b*SEQ + t0)*DSTATE;
  const float* dAb = dAv + (size_t)dir*DTN + ((size_t)b*SEQ + t0)*NH + h;
  unsigned short* yb = y + (size_t)dir*YN + ((size_t)b*SEQ + t0)*DIN + h*HD;
#pragma unroll
  for (int k = 0; k < (CT*16)/64; k++){
    int i = p + k*64;
    ((float*)sC)[i] = Cb[i];
  }
  sdA[p] = dAb[(size_t)p*NH];
  __syncthreads();

  float cp = 1.f;
  float ycur[16], ynxt[16];
#pragma unroll
  for (int j = 0; j < 16; j++) ycur[j] = bf2f(yb[(size_t)j*DIN + p]);
  for (int tt = 0; tt < CT; tt += 16){
    bool pf = (tt + 16 < CT);
    if (pf){
#pragma unroll
      for (int j = 0; j < 16; j++) ynxt[j] = bf2f(yb[(size_t)(tt+16+j)*DIN + p]);
    }
#pragma unroll
    for (int j = 0; j < 16; j++){
      int t = tt + j;
      cp *= sdA[t];
      float4 c0 = *(const float4*)&sC[t][0];
      float4 c1 = *(const float4*)&sC[t][4];
      float4 c2 = *(const float4*)&sC[t][8];
      float4 c3 = *(const float4*)&sC[t][12];
      float a0 = hstart[0]*c0.x;  a0 = fmaf(hstart[1],  c0.y, a0);
      a0 = fmaf(hstart[2],  c0.z, a0); a0 = fmaf(hstart[3],  c0.w, a0);
      float a1 = hstart[4]*c1.x;  a1 = fmaf(hstart[5],  c1.y, a1);
      a1 = fmaf(hstart[6],  c1.z, a1); a1 = fmaf(hstart[7],  c1.w, a1);
      float a2 = hstart[8]*c2.x;  a2 = fmaf(hstart[9],  c2.y, a2);
      a2 = fmaf(hstart[10], c2.z, a2); a2 = fmaf(hstart[11], c2.w, a2);
      float a3 = hstart[12]*c3.x; a3 = fmaf(hstart[13], c3.y, a3);
      a3 = fmaf(hstart[14], c3.z, a3); a3 = fmaf(hstart[15], c3.w, a3);
      float dot = (a0+a1)+(a2+a3);
      yb[(size_t)t*DIN + p] = f2bf(ycur[j] + cp*dot);
    }
    if (pf){
#pragma unroll
      for (int j = 0; j < 16; j++) ycur[j] = ynxt[j];
    }
  }
}

// ---------------- y(already incl D*x) * silu(z); rmsnorm(1024); out bf16 ----------------
__global__ __launch_bounds__(256)
void gated_rms_k(const unsigned short* __restrict__ y,
                 const unsigned short* __restrict__ zxb,
                 const float* __restrict__ nw0, const float* __restrict__ nw1,
                 unsigned short* __restrict__ out){
  __shared__ float sbuf[4];
  int r = blockIdx.x;
  int dir = blockIdx.y;
  const float* normw = dir ? nw1 : nw0;
  const unsigned short* yr = y + (size_t)dir*YN + (size_t)r*DIN;
  const unsigned short* zr = zxb + (size_t)dir*ZXBN + (size_t)r*ZXW;
  unsigned short* outr = out + (size_t)dir*((size_t)ROWS*DIN) + (size_t)r*DIN;
  int d0 = threadIdx.x*4;
  ushort4 yu4 = *(const ushort4*)&yr[d0];
  ushort4 zu4 = *(const ushort4*)&zr[d0];
  float vals[4]; float ss = 0.f;
  float yv[4] = {bf2f(yu4.x), bf2f(yu4.y), bf2f(yu4.z), bf2f(yu4.w)};
  float zv[4] = {bf2f(zu4.x), bf2f(zu4.y), bf2f(zu4.z), bf2f(zu4.w)};
#pragma unroll
  for (int i = 0; i < 4; i++){
    float g = yv[i] * (zv[i]*sigf(zv[i]));
    vals[i] = g; ss += g*g;
  }
  ss = block_reduce_256(ss, sbuf);
  float rs = rsqrtf(ss*(1.f/DIN) + 1e-5f);
  ushort4 o;
  o.x = f2bf(normw[d0+0]*vals[0]*rs);
  o.y = f2bf(normw[d0+1]*vals[1]*rs);
  o.z = f2bf(normw[d0+2]*vals[2]*rs);
  o.w = f2bf(normw[d0+3]*vals[3]*rs);
  *(ushort4*)&outr[d0] = o;
}

// ---------------- hsum = outf + flip(outb) + hid; h2_bf = rmsnorm(hsum) ----------------
__global__ __launch_bounds__(256)
void addres_rms_k(const float* __restrict__ outf, const float* __restrict__ outb,
                  const float* __restrict__ hid, const float* __restrict__ w,
                  float* __restrict__ hsum, unsigned short* __restrict__ h2b){
  __shared__ float sbuf[4];
  int r = blockIdx.x;
  int l = r & (SEQ-1);
  int rb = (r - l) + ((SEQ-1) - l);
  float vals[2]; float ss = 0.f;
#pragma unroll
  for (int i = 0; i < 2; i++){
    int d = threadIdx.x + i*256;
    float v = outf[(size_t)r*DM + d] + outb[(size_t)rb*DM + d] + hid[(size_t)r*DM + d];
    hsum[(size_t)r*DM + d] = v;
    vals[i] = v; ss += v*v;
  }
  ss = block_reduce_256(ss, sbuf);
  float rs = rsqrtf(ss*(1.f/DM) + 1e-6f);
#pragma unroll
  for (int i = 0; i < 2; i++){
    int d = threadIdx.x + i*256;
    h2b[(size_t)r*DM + d] = f2bf(w[d]*vals[i]*rs);
  }
}

extern "C" void kernel_launch(void* const* d_in, const int* in_sizes, int n_in,
                              void* d_out, int out_size, void* d_ws, size_t ws_size,
                              hipStream_t stream){
  const float* hid     = (const float*)d_in[0];
  const float* norm1_w = (const float*)d_in[1];
  const float* wfc_w   = (const float*)d_in[2];
  const float* wfc_b   = (const float*)d_in[3];
  const float* gfc_w   = (const float*)d_in[4];
  const float* gfc_b   = (const float*)d_in[5];
  const float* norm2_w = (const float*)d_in[6];
  const float* fc1_w   = (const float*)d_in[7];
  const float* fc1_b   = (const float*)d_in[8];
  const float* fc2_w   = (const float*)d_in[9];
  const float* fc2_b   = (const float*)d_in[10];
  const float* inproj[2]  = {(const float*)d_in[11], (const float*)d_in[19]};
  const float* convw[2]   = {(const float*)d_in[12], (const float*)d_in[20]};
  const float* convb[2]   = {(const float*)d_in[13], (const float*)d_in[21]};
  const float* dtbias[2]  = {(const float*)d_in[14], (const float*)d_in[22]};
  const float* Alog[2]    = {(const float*)d_in[15], (const float*)d_in[23]};
  const float* Dp[2]      = {(const float*)d_in[16], (const float*)d_in[24]};
  const float* normw[2]   = {(const float*)d_in[17], (const float*)d_in[25]};
  const float* outproj[2] = {(const float*)d_in[18], (const float*)d_in[26]};

  float* ws = (float*)d_ws;
  unsigned short* zxb = (unsigned short*)ws;          // 2 x 4096x2176 bf16 = 8,912,896 f
  float* Bmb   = ws + 8912896;              // 131,072 f
  float* Cmb   = Bmb + 2*BCN;               // 131,072 f
  float* dtv   = Cmb + 2*BCN;               // 131,072 f
  float* dAv   = dtv + 2*DTN;               // 131,072 f
  float* ysc   = dAv + 2*DTN;               // ysc bf16: 4,194,304 f, then Ps
  unsigned short* ysc_b = (unsigned short*)ysc;
  float* Ps    = ysc + 4194304;             // 2,048 f
  float* outd  = Ps + 2048;                 // 4,194,304 f (dir-strided 2,097,152)
  float* hsum  = outd + 4194304;            // 2,097,152 f (hosts Hs during scan)
  float* hnorm = hsum + 2097152;            // 2,097,152 f
  unsigned short* hnorm_bf = (unsigned short*)(hnorm + 2097152);           // 1,048,576 f
  unsigned short* ysc_bf   = (unsigned short*)(hnorm + 2097152 + 1048576); // 4,194,304 f
  unsigned short* wbf      = (unsigned short*)(hnorm + 2097152 + 1048576 + 4194304); // 2,686,976 f
  float* Hs = hsum;                          // 2*HSN floats (scan phase only)
  unsigned short* a1_bf = (unsigned short*)zxb;   // zxb free after gated_rms
  unsigned short* h2_bf = (unsigned short*)ysc;   // ysc free after gated_rms
  unsigned short* wi0 = wbf,            * wi1 = wbf + 1114112;   // 2176x512 each
  unsigned short* wo0 = wbf + 2228224,  * wo1 = wbf + 2752512;   // 512x1024 each
  unsigned short* wf1 = wbf + 3276800;                            // 2048x512
  unsigned short* wf2 = wbf + 4325376;                            // 512x2048
  size_t need_bytes = (size_t)29952000*4;
  if (ws_size < need_bytes) return;

  // weight casts: inproj padded to 2176, rest flat
  castpad2_k<<<(2*2176*512)/256, 256, 0, stream>>>(inproj[0], inproj[1], wi0, wi1, 2096, 512, 2176);
  Cast6 cp;
  cp.src[0] = outproj[0]; cp.dst[0] = wo0; cp.n[0] = 512*1024;
  cp.src[1] = outproj[1]; cp.dst[1] = wo1; cp.n[1] = 512*1024;
  cp.src[2] = fc1_w; cp.dst[2] = wf1; cp.n[2] = 2048*512;
  cp.src[3] = fc2_w; cp.dst[3] = wf2; cp.n[3] = 512*2048;
  cp.src[4] = fc2_w; cp.dst[4] = wf2; cp.n[4] = 0;
  cp.src[5] = fc2_w; cp.dst[5] = wf2; cp.n[5] = 0;
  cast6_k<<<dim3((2048*512/4)/256, 4), 256, 0, stream>>>(cp);

  rmsnorm512_k<<<ROWS, 256, 0, stream>>>(hid, norm1_w, hnorm, hnorm_bf, 1e-6f);
  gated_fusion_k<<<BSZ*(SEQ/16), 256, 0, stream>>>(hnorm, hnorm_bf, wfc_w, wfc_b, gfc_w, gfc_b);

  // inproj both dirs: 4096x2176x512, 8-wave 128x128, DEPTH=2/NBUF=2
  mgemm_k<8,2,4,4,2,2,2><<<dim3(2176/128, 4096/128, 2), 512, 0, stream>>>(
      hnorm_bf, 0, wi0, wi1, nullptr, nullptr, nullptr, nullptr, zxb, ZXBN,
      512, ZXW, -1, 0);
  convbc_dt_k<<<dim3(ROWS/4, 2), 128, 0, stream>>>(
      zxb, convw[0], convw[1], convb[0], convb[1], dtbias[0], dtbias[1],
      Alog[0], Alog[1], Bmb, Cmb, dtv, dAv);
  scanA_k<<<2*BSZ*NH*NCH, 64, 0, stream>>>(
      zxb, Bmb, Cmb, dtv, dAv, convw[0], convw[1], convb[0], convb[1],
      Dp[0], Dp[1], ysc_b, Hs, Ps);
  scanC_k<<<2*BSZ*NH*NCH, 64, 0, stream>>>(Cmb, dAv, Hs, Ps, ysc_b);
  gated_rms_k<<<dim3(ROWS, 2), 256, 0, stream>>>(
      ysc_b, zxb, normw[0], normw[1], ysc_bf);
  // outproj both dirs: 64x64 tile, depth-3/4buf
  mgemm_k<8,2,4,2,1,3,4><<<dim3(512/64, 4096/64, 2), 512, 0, stream>>>(
      ysc_bf, (size_t)ROWS*DIN, wo0, wo1, nullptr, nullptr, nullptr,
      outd, nullptr, 2097152, 1024, DM, 0, 0);

  addres_rms_k<<<ROWS, 256, 0, stream>>>(outd, outd + 2097152, hid, norm2_w, hsum, h2_bf);
  mgemm_k<8,2,4,4,2,3,3><<<dim3(2048/128, 4096/128, 1), 512, 0, stream>>>(
      h2_bf, 0, wf1, wf1, fc1_b, nullptr, nullptr, nullptr, a1_bf, 0,
      512, DFF, 0, 1);
  mgemm_k<8,2,4,2,1,3,4><<<dim3(512/64, 4096/64, 1), 512, 0, stream>>>(
      a1_bf, 0, wf2, wf2, fc2_b, hsum, hid, (float*)d_out, nullptr, 0,
      2048, DM, 0, 0);
}